// Round 1
// baseline (1595.161 us; speedup 1.0000x reference)
//
#include <hip/hip_runtime.h>
#include <math.h>

// ---------------- constants ----------------
#define S_ 2
#define B_ 8
#define N_ 12
#define A_ 4
#define L_ 24
#define C_ 256
#define AUX_ 16
#define EK_ 64
#define K_ 256
#define M_ 8
#define OTH_ 32
#define D2_ 272
#define FF_ 2048
#define RIN_ 736
#define NSTR_ (S_*B_*N_*A_)   // 768

// ---------------- K0: renorm char table (max_norm=1) ----------------
__global__ void scale_table_k(const float* __restrict__ tbl, float* __restrict__ out) {
    int r = blockIdx.x;          // 128 rows
    int c = threadIdx.x;         // 256
    float v = tbl[r * C_ + c];
    float sq = v * v;
    for (int off = 32; off; off >>= 1) sq += __shfl_down(sq, off);
    __shared__ float red[4];
    __shared__ float scl;
    if ((c & 63) == 0) red[c >> 6] = sq;
    __syncthreads();
    if (c == 0) {
        float n = sqrtf(red[0] + red[1] + red[2] + red[3]);
        scl = fminf(1.f, 1.f / fmaxf(n, 1e-7f));
    }
    __syncthreads();
    out[r * C_ + c] = v * scl;
}

// ---------------- K1: gated conv / keyword path -> x1 layout ----------------
// one block per string (s,b,n,a); writes x1[n*64 + sb*4 + a][c]
__global__ void attvec_k(const int* __restrict__ chars, const int* __restrict__ att_type,
                         const int* __restrict__ kw_idx, const float* __restrict__ tblS,
                         const float* __restrict__ fw, const float* __restrict__ fb,
                         const float* __restrict__ gw, const float* __restrict__ gb,
                         const float* __restrict__ mw, const float* __restrict__ mb,
                         const float* __restrict__ kwt, const float* __restrict__ aw,
                         const float* __restrict__ ab, float* __restrict__ x1) {
    int str = blockIdx.x;        // 0..767
    int c = threadIdx.x;         // 0..255
    __shared__ int ch[L_];
    if (c < L_) ch[c] = chars[str * L_ + c];
    __syncthreads();

    int a = str & 3;
    int n = (str >> 2) % N_;
    int sb = str / (N_ * A_);    // s*8+b
    int row = n * 64 + sb * 4 + a;

    float out;
    if (att_type[str] == 1) {
        const float* kr = kwt + kw_idx[str] * EK_;
        const float* awr = aw + c * EK_;
        float acc = ab[c];
        for (int e = 0; e < EK_; ++e) acc += kr[e] * awr[e];
        out = acc;
    } else {
        float xv[L_];
        for (int l = 0; l < L_; ++l) xv[l] = tblS[ch[l] * C_ + c];
        float ssum = 0.f;
        for (int l = 0; l < L_; ++l) {
            float xm = (l > 0) ? xv[l - 1] : 0.f;
            float x0 = xv[l];
            float xp = (l < L_ - 1) ? xv[l + 1] : 0.f;
            float vv = mb[0];
            #pragma unroll
            for (int o = 0; o < 16; ++o) {
                float pf = fb[o] + fw[o*3]*xm + fw[o*3+1]*x0 + fw[o*3+2]*xp;
                float pg = gb[o] + gw[o*3]*xm + gw[o*3+1]*x0 + gw[o*3+2]*xp;
                float t = tanhf(pf);
                float s = 1.f / (1.f + expf(-pg));
                vv += mw[o] * t * s;
            }
            ssum += vv;
        }
        out = ssum * (1.f / 24.f);
    }
    x1[row * C_ + c] = out;
}

// ---------------- generic GEMM: C[r,n] = A[r,:] . W[n,:] + bias[n] ----------------
__global__ void gemm_bias_k(const float* __restrict__ A, const float* __restrict__ W,
                            const float* __restrict__ bias, float* __restrict__ C,
                            int R, int K, int N, int relu) {
    __shared__ float As[32][33];
    __shared__ float Ws[32][33];
    int tid = threadIdx.x;                 // 256
    int bn = blockIdx.x, bm = blockIdx.y;
    int col = bn * 32 + (tid & 31);
    int row0 = bm * 32;
    float acc[4] = {0.f, 0.f, 0.f, 0.f};
    int nt = (K + 31) / 32;
    for (int t = 0; t < nt; ++t) {
        int k0 = t * 32;
        #pragma unroll
        for (int i = 0; i < 4; ++i) {
            int e = tid + i * 256;
            int r = e >> 5, cc = e & 31;
            int gr = row0 + r, gc = k0 + cc;
            As[r][cc] = (gr < R && gc < K) ? A[gr * K + gc] : 0.f;
            int gn = bn * 32 + r;
            Ws[r][cc] = (gn < N && gc < K) ? W[gn * K + gc] : 0.f;
        }
        __syncthreads();
        int rr = tid >> 5;
        #pragma unroll 8
        for (int kk = 0; kk < 32; ++kk) {
            float w = Ws[tid & 31][kk];
            #pragma unroll
            for (int i = 0; i < 4; ++i) acc[i] += As[rr + i * 8][kk] * w;
        }
        __syncthreads();
    }
    if (col < N) {
        float bv = bias[col];
        int rr = tid >> 5;
        #pragma unroll
        for (int i = 0; i < 4; ++i) {
            int gr = row0 + rr + i * 8;
            if (gr < R) {
                float v = acc[i] + bv;
                if (relu) v = fmaxf(v, 0.f);
                C[gr * N + col] = v;
            }
        }
    }
}

// ---------------- attention: one block per batch column j ----------------
// qkv rows r = s*batch + j, row stride 3*d; q at +0, k at +d, v at +2d
__global__ void attn_k(const float* __restrict__ qkv, float* __restrict__ o,
                       int seq, int batch, int d, float scale) {
    __shared__ float sm[3 * 12 * 256];
    __shared__ float sc[12 * 12];
    int j = blockIdx.x, tid = threadIdx.x;
    int sd = seq * d, s3 = 3 * d;
    float* qs = sm;
    float* ks = sm + sd;
    float* vs = sm + 2 * sd;
    for (int idx = tid; idx < sd; idx += 256) {
        int s = idx / d, c = idx - s * d;
        const float* base = qkv + (size_t)(s * batch + j) * s3 + c;
        qs[idx] = base[0];
        ks[idx] = base[d];
        vs[idx] = base[2 * d];
    }
    __syncthreads();
    for (int p = tid; p < seq * seq; p += 256) {
        int s = p / seq, t = p - s * seq;
        float acc = 0.f;
        const float* qp = qs + s * d;
        const float* kp = ks + t * d;
        for (int c = 0; c < d; ++c) acc += qp[c] * kp[c];
        sc[p] = acc * scale;
    }
    __syncthreads();
    if (tid < seq) {
        float m = -1e30f;
        for (int t = 0; t < seq; ++t) m = fmaxf(m, sc[tid * seq + t]);
        float ssum = 0.f;
        for (int t = 0; t < seq; ++t) {
            float e = expf(sc[tid * seq + t] - m);
            sc[tid * seq + t] = e;
            ssum += e;
        }
        float inv = 1.f / ssum;
        for (int t = 0; t < seq; ++t) sc[tid * seq + t] *= inv;
    }
    __syncthreads();
    for (int c = tid; c < d; c += 256) {
        for (int s = 0; s < seq; ++s) {
            float acc = 0.f;
            for (int t = 0; t < seq; ++t) acc += sc[s * seq + t] * vs[t * d + c];
            o[(size_t)(s * batch + j) * d + c] = acc;
        }
    }
}

// ---------------- fused residual + LayerNorm (in place on x) ----------------
__global__ void add_ln_k(float* __restrict__ x, const float* __restrict__ a,
                         const float* __restrict__ g, const float* __restrict__ b, int d) {
    int r = blockIdx.x, tid = threadIdx.x;
    __shared__ float red[10];
    const float* xr = x + (size_t)r * d;
    const float* ar = a + (size_t)r * d;
    int i0 = tid, i1 = tid + 256;
    bool h0 = i0 < d, h1 = i1 < d;
    float v0 = h0 ? (xr[i0] + ar[i0]) : 0.f;
    float v1 = h1 ? (xr[i1] + ar[i1]) : 0.f;
    float s = v0 + v1, ss = v0 * v0 + v1 * v1;
    for (int off = 32; off; off >>= 1) {
        s += __shfl_down(s, off);
        ss += __shfl_down(ss, off);
    }
    if ((tid & 63) == 0) { red[(tid >> 6) * 2] = s; red[(tid >> 6) * 2 + 1] = ss; }
    __syncthreads();
    if (tid == 0) {
        float S = red[0] + red[2] + red[4] + red[6];
        float SS = red[1] + red[3] + red[5] + red[7];
        float mu = S / d;
        float var = SS / d - mu * mu;
        red[8] = mu;
        red[9] = rsqrtf(var + 1e-5f);
    }
    __syncthreads();
    float mu = red[8], inv = red[9];
    float* xw = x + (size_t)r * d;
    if (h0) xw[i0] = (v0 - mu) * inv * g[i0] + b[i0];
    if (h1) xw[i1] = (v1 - mu) * inv * g[i1] + b[i1];
}

// ---------------- build x2: mean over attrs + concat static ----------------
__global__ void build_x2_k(const float* __restrict__ y1, const float* __restrict__ stat,
                           float* __restrict__ x2) {
    int id = blockIdx.x;                 // (s*8+b)*12+n, 192 blocks
    int n = id % N_;
    int b = (id / N_) % B_;
    int s = id / (N_ * B_);
    int orow = b * (S_ * N_) + s * N_ + n;
    for (int c = threadIdx.x; c < D2_; c += 256) {
        float v;
        if (c < C_) {
            int j0 = (s * B_ + b) * A_;
            float acc = 0.f;
            for (int a = 0; a < A_; ++a) acc += y1[(size_t)(n * 64 + j0 + a) * C_ + c];
            v = acc * 0.25f;
        } else {
            v = stat[((size_t)(s * B_ + b) * N_ + n) * AUX_ + (c - C_)];
        }
        x2[(size_t)orow * D2_ + c] = v;
    }
}

// ---------------- build real: mean over nodes ----------------
__global__ void build_real_k(const float* __restrict__ y2, float* __restrict__ real) {
    int id = blockIdx.x;                 // b*2+s, 16 blocks
    int s = id & 1, b = id >> 1;
    for (int c = threadIdx.x; c < D2_; c += 256) {
        float acc = 0.f;
        for (int n = 0; n < N_; ++n) acc += y2[(size_t)(b * 24 + s * N_ + n) * D2_ + c];
        real[(size_t)(b * 2 + s) * D2_ + c] = acc * (1.f / 12.f);
    }
}

// ---------------- regressor: build feats + 2-layer MLP ----------------
__global__ void regressor_k(const float* __restrict__ real, const int* __restrict__ input_idx,
                            const float* __restrict__ kwt, const float* __restrict__ other,
                            const float* __restrict__ w1, const float* __restrict__ b1,
                            const float* __restrict__ w2, const float* __restrict__ b2,
                            float* __restrict__ out) {
    int b = blockIdx.x;                  // 8
    int tid = threadIdx.x;               // 256
    __shared__ float feats[RIN_];
    __shared__ float hh[32];
    for (int i = tid; i < RIN_; i += 256) {
        float v;
        if (i < 64) {
            float acc = 0.f;
            for (int m = 0; m < M_; ++m) acc += kwt[input_idx[b * M_ + m] * EK_ + i];
            v = acc * 0.125f;
        } else if (i < 336) {
            v = real[(size_t)(b * 2 + 0) * D2_ + (i - 64)];
        } else if (i < 400) {
            int e = i - 336;
            float acc = 0.f;
            for (int m = 0; m < M_; ++m) acc += kwt[input_idx[64 + b * M_ + m] * EK_ + e];
            v = acc * 0.125f;
        } else if (i < 672) {
            v = real[(size_t)(b * 2 + 1) * D2_ + (i - 400)];
        } else {
            v = other[b * 64 + (i - 672)];
        }
        feats[i] = v;
    }
    __syncthreads();
    if (tid < 32) {
        float acc = b1[tid];
        const float* wr = w1 + (size_t)tid * RIN_;
        for (int i = 0; i < RIN_; ++i) acc += feats[i] * wr[i];
        hh[tid] = fmaxf(acc, 0.f);
    }
    __syncthreads();
    if (tid == 0) {
        float acc = b2[0];
        for (int j = 0; j < 32; ++j) acc += hh[j] * w2[j];
        out[b] = acc;
    }
}

// ---------------- host ----------------
extern "C" void kernel_launch(void* const* d_in, const int* in_sizes, int n_in,
                              void* d_out, int out_size, void* d_ws, size_t ws_size,
                              hipStream_t stream) {
    const int*   chars      = (const int*)d_in[0];
    const int*   att_type   = (const int*)d_in[1];
    const int*   kw_idx     = (const int*)d_in[2];
    const int*   input_idx  = (const int*)d_in[3];
    const float* stat       = (const float*)d_in[4];
    const float* other      = (const float*)d_in[5];
    const float* char_table = (const float*)d_in[6];
    const float* filter_w   = (const float*)d_in[7];
    const float* filter_b   = (const float*)d_in[8];
    const float* gate_w     = (const float*)d_in[9];
    const float* gate_b     = (const float*)d_in[10];
    const float* mlp_w      = (const float*)d_in[11];
    const float* mlp_b      = (const float*)d_in[12];
    const float* kw_table   = (const float*)d_in[13];
    const float* aline_w    = (const float*)d_in[14];
    const float* aline_b    = (const float*)d_in[15];
    const float* t1_attn_w  = (const float*)d_in[16];
    const float* t1_attn_b  = (const float*)d_in[17];
    const float* t1_ffn_w1  = (const float*)d_in[18];
    const float* t1_ffn_b1  = (const float*)d_in[19];
    const float* t1_ffn_w2  = (const float*)d_in[20];
    const float* t1_ffn_b2  = (const float*)d_in[21];
    const float* t1_ln_g    = (const float*)d_in[22];
    const float* t1_ln_b    = (const float*)d_in[23];
    const float* t2_attn_w  = (const float*)d_in[24];
    const float* t2_attn_b  = (const float*)d_in[25];
    const float* t2_ffn_w1  = (const float*)d_in[26];
    const float* t2_ffn_b1  = (const float*)d_in[27];
    const float* t2_ffn_w2  = (const float*)d_in[28];
    const float* t2_ffn_b2  = (const float*)d_in[29];
    const float* t2_ln_g    = (const float*)d_in[30];
    const float* t2_ln_b    = (const float*)d_in[31];
    const float* reg_w1     = (const float*)d_in[32];
    const float* reg_b1     = (const float*)d_in[33];
    const float* reg_w2     = (const float*)d_in[34];
    const float* reg_b2     = (const float*)d_in[35];

    float* ws   = (float*)d_ws;
    float* tblS = ws;                    // 32768
    float* x1   = tblS + 32768;          // 768*256  = 196608
    float* qkv  = x1 + 196608;           // 768*768  = 589824
    float* obuf = qkv + 589824;          // 196608
    float* abuf = obuf + 196608;         // 196608
    float* hbuf = abuf + 196608;         // 768*2048 = 1572864
    float* x2   = hbuf + 1572864;        // 192*272  = 52224
    float* realb= x2 + 52224;            // 16*272   = 4352

    auto gemm = [&](const float* A, const float* W, const float* bias, float* Cc,
                    int R, int K, int N, int relu) {
        dim3 g((N + 31) / 32, (R + 31) / 32);
        gemm_bias_k<<<g, 256, 0, stream>>>(A, W, bias, Cc, R, K, N, relu);
    };

    scale_table_k<<<128, 256, 0, stream>>>(char_table, tblS);
    attvec_k<<<NSTR_, 256, 0, stream>>>(chars, att_type, kw_idx, tblS,
                                        filter_w, filter_b, gate_w, gate_b,
                                        mlp_w, mlp_b, kw_table, aline_w, aline_b, x1);

    // ---- transformer 1: seq=12, batch=64, d=256 ----
    for (int i = 0; i < 2; ++i) {
        const float* aw = t1_attn_w + (size_t)i * 4 * C_ * C_;
        const float* ab = t1_attn_b + (size_t)i * 4 * C_;
        gemm(x1, aw, ab, qkv, 768, C_, 3 * C_, 0);
        attn_k<<<64, 256, 0, stream>>>(qkv, obuf, 12, 64, C_, 0.0625f);
        gemm(obuf, aw + 3 * C_ * C_, ab + 3 * C_, abuf, 768, C_, C_, 0);
        add_ln_k<<<768, 256, 0, stream>>>(x1, abuf, t1_ln_g + i * 2 * C_, t1_ln_b + i * 2 * C_, C_);
        gemm(x1, t1_ffn_w1 + (size_t)i * FF_ * C_, t1_ffn_b1 + i * FF_, hbuf, 768, C_, FF_, 1);
        gemm(hbuf, t1_ffn_w2 + (size_t)i * C_ * FF_, t1_ffn_b2 + i * C_, abuf, 768, FF_, C_, 0);
        add_ln_k<<<768, 256, 0, stream>>>(x1, abuf, t1_ln_g + i * 2 * C_ + C_, t1_ln_b + i * 2 * C_ + C_, C_);
    }

    build_x2_k<<<192, 256, 0, stream>>>(x1, stat, x2);

    // ---- transformer 2: seq=8, batch=24, d=272 ----
    float sc2 = 1.0f / sqrtf(272.0f);
    for (int i = 0; i < 2; ++i) {
        const float* aw = t2_attn_w + (size_t)i * 4 * D2_ * D2_;
        const float* ab = t2_attn_b + (size_t)i * 4 * D2_;
        gemm(x2, aw, ab, qkv, 192, D2_, 3 * D2_, 0);
        attn_k<<<24, 256, 0, stream>>>(qkv, obuf, 8, 24, D2_, sc2);
        gemm(obuf, aw + 3 * D2_ * D2_, ab + 3 * D2_, abuf, 192, D2_, D2_, 0);
        add_ln_k<<<192, 256, 0, stream>>>(x2, abuf, t2_ln_g + i * 2 * D2_, t2_ln_b + i * 2 * D2_, D2_);
        gemm(x2, t2_ffn_w1 + (size_t)i * FF_ * D2_, t2_ffn_b1 + i * FF_, hbuf, 192, D2_, FF_, 1);
        gemm(hbuf, t2_ffn_w2 + (size_t)i * D2_ * FF_, t2_ffn_b2 + i * D2_, abuf, 192, FF_, D2_, 0);
        add_ln_k<<<192, 256, 0, stream>>>(x2, abuf, t2_ln_g + i * 2 * D2_ + D2_, t2_ln_b + i * 2 * D2_ + D2_, D2_);
    }

    build_real_k<<<16, 256, 0, stream>>>(x2, realb);
    regressor_k<<<8, 256, 0, stream>>>(realb, input_idx, kw_table, other,
                                       reg_w1, reg_b1, reg_w2, reg_b2, (float*)d_out);
}

// Round 2
// 651.096 us; speedup vs baseline: 2.4500x; 2.4500x over previous
//
#include <hip/hip_runtime.h>
#include <math.h>

// ---------------- constants ----------------
#define S_ 2
#define B_ 8
#define N_ 12
#define A_ 4
#define L_ 24
#define C_ 256
#define AUX_ 16
#define EK_ 64
#define K_ 256
#define M_ 8
#define OTH_ 32
#define D2_ 272
#define FF_ 2048
#define RIN_ 736
#define NSTR_ (S_*B_*N_*A_)   // 768

// ---------------- K0: renorm char table (max_norm=1) ----------------
__global__ void scale_table_k(const float* __restrict__ tbl, float* __restrict__ out) {
    int r = blockIdx.x;          // 128 rows
    int c = threadIdx.x;         // 256
    float v = tbl[r * C_ + c];
    float sq = v * v;
    for (int off = 32; off; off >>= 1) sq += __shfl_down(sq, off);
    __shared__ float red[4];
    __shared__ float scl;
    if ((c & 63) == 0) red[c >> 6] = sq;
    __syncthreads();
    if (c == 0) {
        float n = sqrtf(red[0] + red[1] + red[2] + red[3]);
        scl = fminf(1.f, 1.f / fmaxf(n, 1e-7f));
    }
    __syncthreads();
    out[r * C_ + c] = v * scl;
}

// ---------------- K1: gated conv / keyword path -> x1 layout ----------------
__global__ void attvec_k(const int* __restrict__ chars, const int* __restrict__ att_type,
                         const int* __restrict__ kw_idx, const float* __restrict__ tblS,
                         const float* __restrict__ fw, const float* __restrict__ fb,
                         const float* __restrict__ gw, const float* __restrict__ gb,
                         const float* __restrict__ mw, const float* __restrict__ mb,
                         const float* __restrict__ kwt, const float* __restrict__ aw,
                         const float* __restrict__ ab, float* __restrict__ x1) {
    int str = blockIdx.x;        // 0..767
    int c = threadIdx.x;         // 0..255
    __shared__ int ch[L_];
    if (c < L_) ch[c] = chars[str * L_ + c];
    __syncthreads();

    int a = str & 3;
    int n = (str >> 2) % N_;
    int sb = str / (N_ * A_);    // s*8+b
    int row = n * 64 + sb * 4 + a;

    float out;
    if (att_type[str] == 1) {
        const float* kr = kwt + kw_idx[str] * EK_;
        const float* awr = aw + c * EK_;
        float acc = ab[c];
        for (int e = 0; e < EK_; ++e) acc += kr[e] * awr[e];
        out = acc;
    } else {
        float xv[L_];
        for (int l = 0; l < L_; ++l) xv[l] = tblS[ch[l] * C_ + c];
        float ssum = 0.f;
        for (int l = 0; l < L_; ++l) {
            float xm = (l > 0) ? xv[l - 1] : 0.f;
            float x0 = xv[l];
            float xp = (l < L_ - 1) ? xv[l + 1] : 0.f;
            float vv = mb[0];
            #pragma unroll
            for (int o = 0; o < 16; ++o) {
                float pf = fb[o] + fw[o*3]*xm + fw[o*3+1]*x0 + fw[o*3+2]*xp;
                float pg = gb[o] + gw[o*3]*xm + gw[o*3+1]*x0 + gw[o*3+2]*xp;
                float t = tanhf(pf);
                float s = 1.f / (1.f + expf(-pg));
                vv += mw[o] * t * s;
            }
            ssum += vv;
        }
        out = ssum * (1.f / 24.f);
    }
    x1[row * C_ + c] = out;
}

// ---------------- GEMM: 64x64 tile, 4x4 per thread, transposed LDS staging ----
// C[r,n] = A[r,:] . W[n,:] (+bias, relu). Optional split-K via blockIdx.z:
// when gridDim.z > 1, writes raw partial to C + z*R*N (no bias/relu).
#define BM 64
#define BN 64
#define BKT 32
__global__ void gemm64_k(const float* __restrict__ A, const float* __restrict__ W,
                         const float* __restrict__ bias, float* __restrict__ C,
                         int R, int K, int N, int relu, int kslice) {
    __shared__ float As[BKT][BM + 4];
    __shared__ float Bs[BKT][BN + 4];
    int tid = threadIdx.x;               // 256
    int tn = tid & 15, tm = tid >> 4;    // 16x16 thread grid
    int row0 = blockIdx.y * BM;
    int col0 = blockIdx.x * BN;
    int kbeg = blockIdx.z * kslice;
    int kend = min(kbeg + kslice, K);

    float acc[4][4];
    #pragma unroll
    for (int i = 0; i < 4; ++i)
        #pragma unroll
        for (int j = 0; j < 4; ++j) acc[i][j] = 0.f;

    for (int k0 = kbeg; k0 < kend; k0 += BKT) {
        // stage A^T and W^T tiles (transpose in LDS so inner reads are b128)
        #pragma unroll
        for (int i = 0; i < 2; ++i) {
            int f = tid + i * 256;       // 0..511 float4 chunks per matrix
            int r = f >> 3;              // tile row 0..63
            int kq = f & 7;              // float4 group 0..7
            int kl = kq * 4;
            int gk = k0 + kl;
            int gr = row0 + r;
            float4 v;
            if (gr < R && gk + 3 < kend) {
                v = *(const float4*)(A + (size_t)gr * K + gk);
            } else {
                v.x = (gr < R && gk + 0 < kend) ? A[(size_t)gr * K + gk + 0] : 0.f;
                v.y = (gr < R && gk + 1 < kend) ? A[(size_t)gr * K + gk + 1] : 0.f;
                v.z = (gr < R && gk + 2 < kend) ? A[(size_t)gr * K + gk + 2] : 0.f;
                v.w = (gr < R && gk + 3 < kend) ? A[(size_t)gr * K + gk + 3] : 0.f;
            }
            As[kl + 0][r] = v.x; As[kl + 1][r] = v.y;
            As[kl + 2][r] = v.z; As[kl + 3][r] = v.w;
            int gn = col0 + r;
            float4 w;
            if (gn < N && gk + 3 < kend) {
                w = *(const float4*)(W + (size_t)gn * K + gk);
            } else {
                w.x = (gn < N && gk + 0 < kend) ? W[(size_t)gn * K + gk + 0] : 0.f;
                w.y = (gn < N && gk + 1 < kend) ? W[(size_t)gn * K + gk + 1] : 0.f;
                w.z = (gn < N && gk + 2 < kend) ? W[(size_t)gn * K + gk + 2] : 0.f;
                w.w = (gn < N && gk + 3 < kend) ? W[(size_t)gn * K + gk + 3] : 0.f;
            }
            Bs[kl + 0][r] = w.x; Bs[kl + 1][r] = w.y;
            Bs[kl + 2][r] = w.z; Bs[kl + 3][r] = w.w;
        }
        __syncthreads();
        #pragma unroll
        for (int kk = 0; kk < BKT; ++kk) {
            float4 a4 = *(const float4*)&As[kk][tm * 4];
            float4 b4 = *(const float4*)&Bs[kk][tn * 4];
            acc[0][0] += a4.x * b4.x; acc[0][1] += a4.x * b4.y;
            acc[0][2] += a4.x * b4.z; acc[0][3] += a4.x * b4.w;
            acc[1][0] += a4.y * b4.x; acc[1][1] += a4.y * b4.y;
            acc[1][2] += a4.y * b4.z; acc[1][3] += a4.y * b4.w;
            acc[2][0] += a4.z * b4.x; acc[2][1] += a4.z * b4.y;
            acc[2][2] += a4.z * b4.z; acc[2][3] += a4.z * b4.w;
            acc[3][0] += a4.w * b4.x; acc[3][1] += a4.w * b4.y;
            acc[3][2] += a4.w * b4.z; acc[3][3] += a4.w * b4.w;
        }
        __syncthreads();
    }

    bool direct = (gridDim.z == 1);
    float* outp = direct ? C : (C + (size_t)blockIdx.z * R * N);
    int gc = col0 + tn * 4;
    float4 bv = make_float4(0.f, 0.f, 0.f, 0.f);
    if (direct) {
        bv.x = (gc + 0 < N) ? bias[gc + 0] : 0.f;
        bv.y = (gc + 1 < N) ? bias[gc + 1] : 0.f;
        bv.z = (gc + 2 < N) ? bias[gc + 2] : 0.f;
        bv.w = (gc + 3 < N) ? bias[gc + 3] : 0.f;
    }
    #pragma unroll
    for (int mi = 0; mi < 4; ++mi) {
        int gr = row0 + tm * 4 + mi;
        if (gr >= R) continue;
        float4 o;
        o.x = acc[mi][0] + bv.x; o.y = acc[mi][1] + bv.y;
        o.z = acc[mi][2] + bv.z; o.w = acc[mi][3] + bv.w;
        if (direct && relu) {
            o.x = fmaxf(o.x, 0.f); o.y = fmaxf(o.y, 0.f);
            o.z = fmaxf(o.z, 0.f); o.w = fmaxf(o.w, 0.f);
        }
        if (gc + 3 < N) {
            *(float4*)(outp + (size_t)gr * N + gc) = o;
        } else {
            if (gc + 0 < N) outp[(size_t)gr * N + gc + 0] = o.x;
            if (gc + 1 < N) outp[(size_t)gr * N + gc + 1] = o.y;
            if (gc + 2 < N) outp[(size_t)gr * N + gc + 2] = o.z;
            if (gc + 3 < N) outp[(size_t)gr * N + gc + 3] = o.w;
        }
    }
}

// ---------------- split-K reduce: sum slices + bias + relu ----------------
__global__ void reduce_bias_k(const float* __restrict__ part, const float* __restrict__ bias,
                              float* __restrict__ C, int R, int N, int NS, int relu) {
    int idx = blockIdx.x * 256 + threadIdx.x;
    int tot = R * N;
    if (idx >= tot) return;
    float s = 0.f;
    for (int z = 0; z < NS; ++z) s += part[(size_t)z * tot + idx];
    s += bias[idx % N];
    if (relu) s = fmaxf(s, 0.f);
    C[idx] = s;
}

// ---------------- attention: one block per batch column j ----------------
__global__ void attn_k(const float* __restrict__ qkv, float* __restrict__ o,
                       int seq, int batch, int d, float scale) {
    __shared__ float sm[3 * 12 * 256];
    __shared__ float sc[12 * 12];
    int j = blockIdx.x, tid = threadIdx.x;
    int sd = seq * d, s3 = 3 * d;
    float* qs = sm;
    float* ks = sm + sd;
    float* vs = sm + 2 * sd;
    for (int idx = tid; idx < sd; idx += 256) {
        int s = idx / d, c = idx - s * d;
        const float* base = qkv + (size_t)(s * batch + j) * s3 + c;
        qs[idx] = base[0];
        ks[idx] = base[d];
        vs[idx] = base[2 * d];
    }
    __syncthreads();
    for (int p = tid; p < seq * seq; p += 256) {
        int s = p / seq, t = p - s * seq;
        float acc = 0.f;
        const float* qp = qs + s * d;
        const float* kp = ks + t * d;
        for (int c = 0; c < d; ++c) acc += qp[c] * kp[c];
        sc[p] = acc * scale;
    }
    __syncthreads();
    if (tid < seq) {
        float m = -1e30f;
        for (int t = 0; t < seq; ++t) m = fmaxf(m, sc[tid * seq + t]);
        float ssum = 0.f;
        for (int t = 0; t < seq; ++t) {
            float e = expf(sc[tid * seq + t] - m);
            sc[tid * seq + t] = e;
            ssum += e;
        }
        float inv = 1.f / ssum;
        for (int t = 0; t < seq; ++t) sc[tid * seq + t] *= inv;
    }
    __syncthreads();
    for (int c = tid; c < d; c += 256) {
        for (int s = 0; s < seq; ++s) {
            float acc = 0.f;
            for (int t = 0; t < seq; ++t) acc += sc[s * seq + t] * vs[t * d + c];
            o[(size_t)(s * batch + j) * d + c] = acc;
        }
    }
}

// ---------------- fused residual + LayerNorm (in place on x) ----------------
__global__ void add_ln_k(float* __restrict__ x, const float* __restrict__ a,
                         const float* __restrict__ g, const float* __restrict__ b, int d) {
    int r = blockIdx.x, tid = threadIdx.x;
    __shared__ float red[10];
    const float* xr = x + (size_t)r * d;
    const float* ar = a + (size_t)r * d;
    int i0 = tid, i1 = tid + 256;
    bool h0 = i0 < d, h1 = i1 < d;
    float v0 = h0 ? (xr[i0] + ar[i0]) : 0.f;
    float v1 = h1 ? (xr[i1] + ar[i1]) : 0.f;
    float s = v0 + v1, ss = v0 * v0 + v1 * v1;
    for (int off = 32; off; off >>= 1) {
        s += __shfl_down(s, off);
        ss += __shfl_down(ss, off);
    }
    if ((tid & 63) == 0) { red[(tid >> 6) * 2] = s; red[(tid >> 6) * 2 + 1] = ss; }
    __syncthreads();
    if (tid == 0) {
        float S = red[0] + red[2] + red[4] + red[6];
        float SS = red[1] + red[3] + red[5] + red[7];
        float mu = S / d;
        float var = SS / d - mu * mu;
        red[8] = mu;
        red[9] = rsqrtf(var + 1e-5f);
    }
    __syncthreads();
    float mu = red[8], inv = red[9];
    float* xw = x + (size_t)r * d;
    if (h0) xw[i0] = (v0 - mu) * inv * g[i0] + b[i0];
    if (h1) xw[i1] = (v1 - mu) * inv * g[i1] + b[i1];
}

// ---------------- build x2: mean over attrs + concat static ----------------
__global__ void build_x2_k(const float* __restrict__ y1, const float* __restrict__ stat,
                           float* __restrict__ x2) {
    int id = blockIdx.x;                 // 192 blocks
    int n = id % N_;
    int b = (id / N_) % B_;
    int s = id / (N_ * B_);
    int orow = b * (S_ * N_) + s * N_ + n;
    for (int c = threadIdx.x; c < D2_; c += 256) {
        float v;
        if (c < C_) {
            int j0 = (s * B_ + b) * A_;
            float acc = 0.f;
            for (int a = 0; a < A_; ++a) acc += y1[(size_t)(n * 64 + j0 + a) * C_ + c];
            v = acc * 0.25f;
        } else {
            v = stat[((size_t)(s * B_ + b) * N_ + n) * AUX_ + (c - C_)];
        }
        x2[(size_t)orow * D2_ + c] = v;
    }
}

// ---------------- build real: mean over nodes ----------------
__global__ void build_real_k(const float* __restrict__ y2, float* __restrict__ real) {
    int id = blockIdx.x;                 // 16 blocks
    int s = id & 1, b = id >> 1;
    for (int c = threadIdx.x; c < D2_; c += 256) {
        float acc = 0.f;
        for (int n = 0; n < N_; ++n) acc += y2[(size_t)(b * 24 + s * N_ + n) * D2_ + c];
        real[(size_t)(b * 2 + s) * D2_ + c] = acc * (1.f / 12.f);
    }
}

// ---------------- regressor: build feats + 2-layer MLP ----------------
__global__ void regressor_k(const float* __restrict__ real, const int* __restrict__ input_idx,
                            const float* __restrict__ kwt, const float* __restrict__ other,
                            const float* __restrict__ w1, const float* __restrict__ b1,
                            const float* __restrict__ w2, const float* __restrict__ b2,
                            float* __restrict__ out) {
    int b = blockIdx.x;                  // 8
    int tid = threadIdx.x;               // 256
    __shared__ float feats[RIN_];
    __shared__ float hh[32];
    for (int i = tid; i < RIN_; i += 256) {
        float v;
        if (i < 64) {
            float acc = 0.f;
            for (int m = 0; m < M_; ++m) acc += kwt[input_idx[b * M_ + m] * EK_ + i];
            v = acc * 0.125f;
        } else if (i < 336) {
            v = real[(size_t)(b * 2 + 0) * D2_ + (i - 64)];
        } else if (i < 400) {
            int e = i - 336;
            float acc = 0.f;
            for (int m = 0; m < M_; ++m) acc += kwt[input_idx[64 + b * M_ + m] * EK_ + e];
            v = acc * 0.125f;
        } else if (i < 672) {
            v = real[(size_t)(b * 2 + 1) * D2_ + (i - 400)];
        } else {
            v = other[b * 64 + (i - 672)];
        }
        feats[i] = v;
    }
    __syncthreads();
    if (tid < 32) {
        float acc = b1[tid];
        const float* wr = w1 + (size_t)tid * RIN_;
        for (int i = 0; i < RIN_; ++i) acc += feats[i] * wr[i];
        hh[tid] = fmaxf(acc, 0.f);
    }
    __syncthreads();
    if (tid == 0) {
        float acc = b2[0];
        for (int j = 0; j < 32; ++j) acc += hh[j] * w2[j];
        out[b] = acc;
    }
}

// ---------------- host ----------------
extern "C" void kernel_launch(void* const* d_in, const int* in_sizes, int n_in,
                              void* d_out, int out_size, void* d_ws, size_t ws_size,
                              hipStream_t stream) {
    const int*   chars      = (const int*)d_in[0];
    const int*   att_type   = (const int*)d_in[1];
    const int*   kw_idx     = (const int*)d_in[2];
    const int*   input_idx  = (const int*)d_in[3];
    const float* stat       = (const float*)d_in[4];
    const float* other      = (const float*)d_in[5];
    const float* char_table = (const float*)d_in[6];
    const float* filter_w   = (const float*)d_in[7];
    const float* filter_b   = (const float*)d_in[8];
    const float* gate_w     = (const float*)d_in[9];
    const float* gate_b     = (const float*)d_in[10];
    const float* mlp_w      = (const float*)d_in[11];
    const float* mlp_b      = (const float*)d_in[12];
    const float* kw_table   = (const float*)d_in[13];
    const float* aline_w    = (const float*)d_in[14];
    const float* aline_b    = (const float*)d_in[15];
    const float* t1_attn_w  = (const float*)d_in[16];
    const float* t1_attn_b  = (const float*)d_in[17];
    const float* t1_ffn_w1  = (const float*)d_in[18];
    const float* t1_ffn_b1  = (const float*)d_in[19];
    const float* t1_ffn_w2  = (const float*)d_in[20];
    const float* t1_ffn_b2  = (const float*)d_in[21];
    const float* t1_ln_g    = (const float*)d_in[22];
    const float* t1_ln_b    = (const float*)d_in[23];
    const float* t2_attn_w  = (const float*)d_in[24];
    const float* t2_attn_b  = (const float*)d_in[25];
    const float* t2_ffn_w1  = (const float*)d_in[26];
    const float* t2_ffn_b1  = (const float*)d_in[27];
    const float* t2_ffn_w2  = (const float*)d_in[28];
    const float* t2_ffn_b2  = (const float*)d_in[29];
    const float* t2_ln_g    = (const float*)d_in[30];
    const float* t2_ln_b    = (const float*)d_in[31];
    const float* reg_w1     = (const float*)d_in[32];
    const float* reg_b1     = (const float*)d_in[33];
    const float* reg_w2     = (const float*)d_in[34];
    const float* reg_b2     = (const float*)d_in[35];

    float* ws   = (float*)d_ws;
    float* tblS = ws;                    // 32768
    float* x1   = tblS + 32768;          // 768*256  = 196608
    float* qkv  = x1 + 196608;           // 768*768  = 589824
    float* obuf = qkv + 589824;          // 196608  (qkv+obuf contiguous: split-K partials)
    float* abuf = obuf + 196608;         // 196608
    float* hbuf = abuf + 196608;         // 768*2048 = 1572864
    float* x2   = hbuf + 1572864;        // 192*272  = 52224
    float* realb= x2 + 52224;            // 16*272   = 4352
    float* pbuf = qkv;                   // split-K partial region (786432 floats)

    auto gemm = [&](const float* A, const float* W, const float* bias, float* Cc,
                    int R, int K, int N, int relu) {
        dim3 g((N + BN - 1) / BN, (R + BM - 1) / BM, 1);
        gemm64_k<<<g, 256, 0, stream>>>(A, W, bias, Cc, R, K, N, relu, K);
    };
    auto gemm_split = [&](const float* A, const float* W, const float* bias, float* Cc,
                          int R, int K, int N, int relu, int ns) {
        int ksl = ((K + ns - 1) / ns + BKT - 1) / BKT * BKT;
        dim3 g((N + BN - 1) / BN, (R + BM - 1) / BM, ns);
        gemm64_k<<<g, 256, 0, stream>>>(A, W, bias, pbuf, R, K, N, 0, ksl);
        int tot = R * N;
        reduce_bias_k<<<(tot + 255) / 256, 256, 0, stream>>>(pbuf, bias, Cc, R, N, ns, relu);
    };

    scale_table_k<<<128, 256, 0, stream>>>(char_table, tblS);
    attvec_k<<<NSTR_, 256, 0, stream>>>(chars, att_type, kw_idx, tblS,
                                        filter_w, filter_b, gate_w, gate_b,
                                        mlp_w, mlp_b, kw_table, aline_w, aline_b, x1);

    // ---- transformer 1: seq=12, batch=64, d=256 ----
    for (int i = 0; i < 2; ++i) {
        const float* aw = t1_attn_w + (size_t)i * 4 * C_ * C_;
        const float* ab = t1_attn_b + (size_t)i * 4 * C_;
        gemm(x1, aw, ab, qkv, 768, C_, 3 * C_, 0);
        attn_k<<<64, 256, 0, stream>>>(qkv, obuf, 12, 64, C_, 0.0625f);
        gemm(obuf, aw + 3 * C_ * C_, ab + 3 * C_, abuf, 768, C_, C_, 0);
        add_ln_k<<<768, 256, 0, stream>>>(x1, abuf, t1_ln_g + i * 2 * C_, t1_ln_b + i * 2 * C_, C_);
        gemm(x1, t1_ffn_w1 + (size_t)i * FF_ * C_, t1_ffn_b1 + i * FF_, hbuf, 768, C_, FF_, 1);
        gemm_split(hbuf, t1_ffn_w2 + (size_t)i * C_ * FF_, t1_ffn_b2 + i * C_, abuf, 768, FF_, C_, 0, 4);
        add_ln_k<<<768, 256, 0, stream>>>(x1, abuf, t1_ln_g + i * 2 * C_ + C_, t1_ln_b + i * 2 * C_ + C_, C_);
    }

    build_x2_k<<<192, 256, 0, stream>>>(x1, stat, x2);

    // ---- transformer 2: seq=8, batch=24, d=272 ----
    float sc2 = 1.0f / sqrtf(272.0f);
    for (int i = 0; i < 2; ++i) {
        const float* aw = t2_attn_w + (size_t)i * 4 * D2_ * D2_;
        const float* ab = t2_attn_b + (size_t)i * 4 * D2_;
        gemm(x2, aw, ab, qkv, 192, D2_, 3 * D2_, 0);
        attn_k<<<24, 256, 0, stream>>>(qkv, obuf, 8, 24, D2_, sc2);
        gemm(obuf, aw + 3 * D2_ * D2_, ab + 3 * D2_, abuf, 192, D2_, D2_, 0);
        add_ln_k<<<192, 256, 0, stream>>>(x2, abuf, t2_ln_g + i * 2 * D2_, t2_ln_b + i * 2 * D2_, D2_);
        gemm(x2, t2_ffn_w1 + (size_t)i * FF_ * D2_, t2_ffn_b1 + i * FF_, hbuf, 192, D2_, FF_, 1);
        gemm_split(hbuf, t2_ffn_w2 + (size_t)i * D2_ * FF_, t2_ffn_b2 + i * D2_, abuf, 192, FF_, D2_, 0, 8);
        add_ln_k<<<192, 256, 0, stream>>>(x2, abuf, t2_ln_g + i * 2 * D2_ + D2_, t2_ln_b + i * 2 * D2_ + D2_, D2_);
    }

    build_real_k<<<16, 256, 0, stream>>>(x2, realb);
    regressor_k<<<8, 256, 0, stream>>>(realb, input_idx, kw_table, other,
                                       reg_w1, reg_b1, reg_w2, reg_b2, (float*)d_out);
}

// Round 3
// 582.426 us; speedup vs baseline: 2.7388x; 1.1179x over previous
//
#include <hip/hip_runtime.h>
#include <math.h>

// ---------------- constants ----------------
#define S_ 2
#define B_ 8
#define N_ 12
#define A_ 4
#define L_ 24
#define C_ 256
#define AUX_ 16
#define EK_ 64
#define K_ 256
#define M_ 8
#define OTH_ 32
#define D2_ 272
#define FF_ 2048
#define RIN_ 736
#define NSTR_ (S_*B_*N_*A_)   // 768

// fast sigmoid / tanh via native exp + rcp (exact saturation at +-inf)
__device__ __forceinline__ float fast_sig(float x) {
    return __builtin_amdgcn_rcpf(1.f + __expf(-x));
}
__device__ __forceinline__ float fast_tanh(float x) {
    return 1.f - 2.f * __builtin_amdgcn_rcpf(1.f + __expf(2.f * x));
}

// ---------------- K0: renorm char table (max_norm=1) ----------------
__global__ void scale_table_k(const float* __restrict__ tbl, float* __restrict__ out) {
    int r = blockIdx.x;          // 128 rows
    int c = threadIdx.x;         // 256
    float v = tbl[r * C_ + c];
    float sq = v * v;
    for (int off = 32; off; off >>= 1) sq += __shfl_down(sq, off);
    __shared__ float red[4];
    __shared__ float scl;
    if ((c & 63) == 0) red[c >> 6] = sq;
    __syncthreads();
    if (c == 0) {
        float n = sqrtf(red[0] + red[1] + red[2] + red[3]);
        scl = fminf(1.f, 1.f / fmaxf(n, 1e-7f));
    }
    __syncthreads();
    out[r * C_ + c] = v * scl;
}

// ---------------- K1: gated conv / keyword path -> x1 layout ----------------
// o-outer / l-inner: 9 uniform weights per o-iter (SGPR), 24-wide ILP inner.
__global__ void attvec_k(const int* __restrict__ chars, const int* __restrict__ att_type,
                         const int* __restrict__ kw_idx, const float* __restrict__ tblS,
                         const float* __restrict__ fw, const float* __restrict__ fb,
                         const float* __restrict__ gw, const float* __restrict__ gb,
                         const float* __restrict__ mw, const float* __restrict__ mb,
                         const float* __restrict__ kwt, const float* __restrict__ aw,
                         const float* __restrict__ ab, float* __restrict__ x1) {
    int str = blockIdx.x;        // 0..767
    int c = threadIdx.x;         // 0..255
    __shared__ int ch[L_];
    if (c < L_) ch[c] = chars[str * L_ + c];
    __syncthreads();

    int a = str & 3;
    int n = (str >> 2) % N_;
    int sb = str / (N_ * A_);    // s*8+b
    int row = n * 64 + sb * 4 + a;

    float out;
    if (att_type[str] == 1) {
        const float* kr = kwt + kw_idx[str] * EK_;
        const float* awr = aw + c * EK_;
        float acc = ab[c];
        for (int e = 0; e < EK_; ++e) acc += kr[e] * awr[e];
        out = acc;
    } else {
        float xv[L_ + 2];                    // zero-padded embeddings
        xv[0] = 0.f; xv[L_ + 1] = 0.f;
        #pragma unroll
        for (int l = 0; l < L_; ++l) xv[l + 1] = tblS[ch[l] * C_ + c];
        float acc = 0.f;
        #pragma unroll
        for (int o = 0; o < 16; ++o) {
            float f0 = fw[o*3], f1 = fw[o*3+1], f2 = fw[o*3+2], fbv = fb[o];
            float g0 = gw[o*3], g1 = gw[o*3+1], g2 = gw[o*3+2], gbv = gb[o];
            float mwv = mw[o];
            float osum = 0.f;
            #pragma unroll
            for (int l = 1; l <= L_; ++l) {
                float xm = xv[l - 1], x0 = xv[l], xp = xv[l + 1];
                float pf = fbv + f0 * xm + f1 * x0 + f2 * xp;
                float pg = gbv + g0 * xm + g1 * x0 + g2 * xp;
                osum += fast_tanh(pf) * fast_sig(pg);
            }
            acc += mwv * osum;
        }
        out = mb[0] + acc * (1.f / 24.f);
    }
    x1[row * C_ + c] = out;
}

// ---------------- GEMM: 64x64 tile, 4x4 per thread, transposed LDS staging ----
#define BM 64
#define BN 64
#define BKT 32
__global__ void gemm64_k(const float* __restrict__ A, const float* __restrict__ W,
                         const float* __restrict__ bias, float* __restrict__ C,
                         int R, int K, int N, int relu, int kslice) {
    __shared__ float As[BKT][BM + 4];
    __shared__ float Bs[BKT][BN + 4];
    int tid = threadIdx.x;               // 256
    int tn = tid & 15, tm = tid >> 4;    // 16x16 thread grid
    int row0 = blockIdx.y * BM;
    int col0 = blockIdx.x * BN;
    int kbeg = blockIdx.z * kslice;
    int kend = min(kbeg + kslice, K);

    float acc[4][4];
    #pragma unroll
    for (int i = 0; i < 4; ++i)
        #pragma unroll
        for (int j = 0; j < 4; ++j) acc[i][j] = 0.f;

    for (int k0 = kbeg; k0 < kend; k0 += BKT) {
        #pragma unroll
        for (int i = 0; i < 2; ++i) {
            int f = tid + i * 256;       // 0..511 float4 chunks per matrix
            int r = f >> 3;              // tile row 0..63
            int kq = f & 7;              // float4 group 0..7
            int kl = kq * 4;
            int gk = k0 + kl;
            int gr = row0 + r;
            float4 v;
            if (gr < R && gk + 3 < kend) {
                v = *(const float4*)(A + (size_t)gr * K + gk);
            } else {
                v.x = (gr < R && gk + 0 < kend) ? A[(size_t)gr * K + gk + 0] : 0.f;
                v.y = (gr < R && gk + 1 < kend) ? A[(size_t)gr * K + gk + 1] : 0.f;
                v.z = (gr < R && gk + 2 < kend) ? A[(size_t)gr * K + gk + 2] : 0.f;
                v.w = (gr < R && gk + 3 < kend) ? A[(size_t)gr * K + gk + 3] : 0.f;
            }
            As[kl + 0][r] = v.x; As[kl + 1][r] = v.y;
            As[kl + 2][r] = v.z; As[kl + 3][r] = v.w;
            int gn = col0 + r;
            float4 w;
            if (gn < N && gk + 3 < kend) {
                w = *(const float4*)(W + (size_t)gn * K + gk);
            } else {
                w.x = (gn < N && gk + 0 < kend) ? W[(size_t)gn * K + gk + 0] : 0.f;
                w.y = (gn < N && gk + 1 < kend) ? W[(size_t)gn * K + gk + 1] : 0.f;
                w.z = (gn < N && gk + 2 < kend) ? W[(size_t)gn * K + gk + 2] : 0.f;
                w.w = (gn < N && gk + 3 < kend) ? W[(size_t)gn * K + gk + 3] : 0.f;
            }
            Bs[kl + 0][r] = w.x; Bs[kl + 1][r] = w.y;
            Bs[kl + 2][r] = w.z; Bs[kl + 3][r] = w.w;
        }
        __syncthreads();
        #pragma unroll
        for (int kk = 0; kk < BKT; ++kk) {
            float4 a4 = *(const float4*)&As[kk][tm * 4];
            float4 b4 = *(const float4*)&Bs[kk][tn * 4];
            acc[0][0] += a4.x * b4.x; acc[0][1] += a4.x * b4.y;
            acc[0][2] += a4.x * b4.z; acc[0][3] += a4.x * b4.w;
            acc[1][0] += a4.y * b4.x; acc[1][1] += a4.y * b4.y;
            acc[1][2] += a4.y * b4.z; acc[1][3] += a4.y * b4.w;
            acc[2][0] += a4.z * b4.x; acc[2][1] += a4.z * b4.y;
            acc[2][2] += a4.z * b4.z; acc[2][3] += a4.z * b4.w;
            acc[3][0] += a4.w * b4.x; acc[3][1] += a4.w * b4.y;
            acc[3][2] += a4.w * b4.z; acc[3][3] += a4.w * b4.w;
        }
        __syncthreads();
    }

    bool direct = (gridDim.z == 1);
    float* outp = direct ? C : (C + (size_t)blockIdx.z * R * N);
    int gc = col0 + tn * 4;
    float4 bv = make_float4(0.f, 0.f, 0.f, 0.f);
    if (direct) {
        bv.x = (gc + 0 < N) ? bias[gc + 0] : 0.f;
        bv.y = (gc + 1 < N) ? bias[gc + 1] : 0.f;
        bv.z = (gc + 2 < N) ? bias[gc + 2] : 0.f;
        bv.w = (gc + 3 < N) ? bias[gc + 3] : 0.f;
    }
    #pragma unroll
    for (int mi = 0; mi < 4; ++mi) {
        int gr = row0 + tm * 4 + mi;
        if (gr >= R) continue;
        float4 o;
        o.x = acc[mi][0] + bv.x; o.y = acc[mi][1] + bv.y;
        o.z = acc[mi][2] + bv.z; o.w = acc[mi][3] + bv.w;
        if (direct && relu) {
            o.x = fmaxf(o.x, 0.f); o.y = fmaxf(o.y, 0.f);
            o.z = fmaxf(o.z, 0.f); o.w = fmaxf(o.w, 0.f);
        }
        if (gc + 3 < N) {
            *(float4*)(outp + (size_t)gr * N + gc) = o;
        } else {
            if (gc + 0 < N) outp[(size_t)gr * N + gc + 0] = o.x;
            if (gc + 1 < N) outp[(size_t)gr * N + gc + 1] = o.y;
            if (gc + 2 < N) outp[(size_t)gr * N + gc + 2] = o.z;
            if (gc + 3 < N) outp[(size_t)gr * N + gc + 3] = o.w;
        }
    }
}

// ---------------- split-K reduce: sum slices + bias + relu ----------------
__global__ void reduce_bias_k(const float* __restrict__ part, const float* __restrict__ bias,
                              float* __restrict__ C, int R, int N, int NS, int relu) {
    int idx = blockIdx.x * 256 + threadIdx.x;
    int tot = R * N;
    if (idx >= tot) return;
    float s = 0.f;
    for (int z = 0; z < NS; ++z) s += part[(size_t)z * tot + idx];
    s += bias[idx % N];
    if (relu) s = fmaxf(s, 0.f);
    C[idx] = s;
}

// ---------------- attention: one block per batch column j ----------------
__global__ void attn_k(const float* __restrict__ qkv, float* __restrict__ o,
                       int seq, int batch, int d, float scale) {
    __shared__ float sm[3 * 12 * 256];
    __shared__ float sc[12 * 12];
    int j = blockIdx.x, tid = threadIdx.x;
    int sd = seq * d, s3 = 3 * d;
    float* qs = sm;
    float* ks = sm + sd;
    float* vs = sm + 2 * sd;
    for (int idx = tid; idx < sd; idx += 256) {
        int s = idx / d, c = idx - s * d;
        const float* base = qkv + (size_t)(s * batch + j) * s3 + c;
        qs[idx] = base[0];
        ks[idx] = base[d];
        vs[idx] = base[2 * d];
    }
    __syncthreads();
    for (int p = tid; p < seq * seq; p += 256) {
        int s = p / seq, t = p - s * seq;
        float acc = 0.f;
        const float* qp = qs + s * d;
        const float* kp = ks + t * d;
        for (int c = 0; c < d; ++c) acc += qp[c] * kp[c];
        sc[p] = acc * scale;
    }
    __syncthreads();
    if (tid < seq) {
        float m = -1e30f;
        for (int t = 0; t < seq; ++t) m = fmaxf(m, sc[tid * seq + t]);
        float ssum = 0.f;
        for (int t = 0; t < seq; ++t) {
            float e = expf(sc[tid * seq + t] - m);
            sc[tid * seq + t] = e;
            ssum += e;
        }
        float inv = 1.f / ssum;
        for (int t = 0; t < seq; ++t) sc[tid * seq + t] *= inv;
    }
    __syncthreads();
    for (int c = tid; c < d; c += 256) {
        for (int s = 0; s < seq; ++s) {
            float acc = 0.f;
            for (int t = 0; t < seq; ++t) acc += sc[s * seq + t] * vs[t * d + c];
            o[(size_t)(s * batch + j) * d + c] = acc;
        }
    }
}

// ---------------- fused residual + LayerNorm (in place on x) ----------------
__global__ void add_ln_k(float* __restrict__ x, const float* __restrict__ a,
                         const float* __restrict__ g, const float* __restrict__ b, int d) {
    int r = blockIdx.x, tid = threadIdx.x;
    __shared__ float red[10];
    const float* xr = x + (size_t)r * d;
    const float* ar = a + (size_t)r * d;
    int i0 = tid, i1 = tid + 256;
    bool h0 = i0 < d, h1 = i1 < d;
    float v0 = h0 ? (xr[i0] + ar[i0]) : 0.f;
    float v1 = h1 ? (xr[i1] + ar[i1]) : 0.f;
    float s = v0 + v1, ss = v0 * v0 + v1 * v1;
    for (int off = 32; off; off >>= 1) {
        s += __shfl_down(s, off);
        ss += __shfl_down(ss, off);
    }
    if ((tid & 63) == 0) { red[(tid >> 6) * 2] = s; red[(tid >> 6) * 2 + 1] = ss; }
    __syncthreads();
    if (tid == 0) {
        float S = red[0] + red[2] + red[4] + red[6];
        float SS = red[1] + red[3] + red[5] + red[7];
        float mu = S / d;
        float var = SS / d - mu * mu;
        red[8] = mu;
        red[9] = rsqrtf(var + 1e-5f);
    }
    __syncthreads();
    float mu = red[8], inv = red[9];
    float* xw = x + (size_t)r * d;
    if (h0) xw[i0] = (v0 - mu) * inv * g[i0] + b[i0];
    if (h1) xw[i1] = (v1 - mu) * inv * g[i1] + b[i1];
}

// ---------------- build x2: mean over attrs + concat static ----------------
__global__ void build_x2_k(const float* __restrict__ y1, const float* __restrict__ stat,
                           float* __restrict__ x2) {
    int id = blockIdx.x;                 // 192 blocks
    int n = id % N_;
    int b = (id / N_) % B_;
    int s = id / (N_ * B_);
    int orow = b * (S_ * N_) + s * N_ + n;
    for (int c = threadIdx.x; c < D2_; c += 256) {
        float v;
        if (c < C_) {
            int j0 = (s * B_ + b) * A_;
            float acc = 0.f;
            for (int a = 0; a < A_; ++a) acc += y1[(size_t)(n * 64 + j0 + a) * C_ + c];
            v = acc * 0.25f;
        } else {
            v = stat[((size_t)(s * B_ + b) * N_ + n) * AUX_ + (c - C_)];
        }
        x2[(size_t)orow * D2_ + c] = v;
    }
}

// ---------------- build real: mean over nodes ----------------
__global__ void build_real_k(const float* __restrict__ y2, float* __restrict__ real) {
    int id = blockIdx.x;                 // 16 blocks
    int s = id & 1, b = id >> 1;
    for (int c = threadIdx.x; c < D2_; c += 256) {
        float acc = 0.f;
        for (int n = 0; n < N_; ++n) acc += y2[(size_t)(b * 24 + s * N_ + n) * D2_ + c];
        real[(size_t)(b * 2 + s) * D2_ + c] = acc * (1.f / 12.f);
    }
}

// ---------------- regressor: build feats + 2-layer MLP ----------------
__global__ void regressor_k(const float* __restrict__ real, const int* __restrict__ input_idx,
                            const float* __restrict__ kwt, const float* __restrict__ other,
                            const float* __restrict__ w1, const float* __restrict__ b1,
                            const float* __restrict__ w2, const float* __restrict__ b2,
                            float* __restrict__ out) {
    int b = blockIdx.x;                  // 8
    int tid = threadIdx.x;               // 256
    __shared__ float feats[RIN_];
    __shared__ float hh[32];
    for (int i = tid; i < RIN_; i += 256) {
        float v;
        if (i < 64) {
            float acc = 0.f;
            for (int m = 0; m < M_; ++m) acc += kwt[input_idx[b * M_ + m] * EK_ + i];
            v = acc * 0.125f;
        } else if (i < 336) {
            v = real[(size_t)(b * 2 + 0) * D2_ + (i - 64)];
        } else if (i < 400) {
            int e = i - 336;
            float acc = 0.f;
            for (int m = 0; m < M_; ++m) acc += kwt[input_idx[64 + b * M_ + m] * EK_ + e];
            v = acc * 0.125f;
        } else if (i < 672) {
            v = real[(size_t)(b * 2 + 1) * D2_ + (i - 400)];
        } else {
            v = other[b * 64 + (i - 672)];
        }
        feats[i] = v;
    }
    __syncthreads();
    if (tid < 32) {
        float acc = b1[tid];
        const float* wr = w1 + (size_t)tid * RIN_;
        for (int i = 0; i < RIN_; ++i) acc += feats[i] * wr[i];
        hh[tid] = fmaxf(acc, 0.f);
    }
    __syncthreads();
    if (tid == 0) {
        float acc = b2[0];
        for (int j = 0; j < 32; ++j) acc += hh[j] * w2[j];
        out[b] = acc;
    }
}

// ---------------- host ----------------
extern "C" void kernel_launch(void* const* d_in, const int* in_sizes, int n_in,
                              void* d_out, int out_size, void* d_ws, size_t ws_size,
                              hipStream_t stream) {
    const int*   chars      = (const int*)d_in[0];
    const int*   att_type   = (const int*)d_in[1];
    const int*   kw_idx     = (const int*)d_in[2];
    const int*   input_idx  = (const int*)d_in[3];
    const float* stat       = (const float*)d_in[4];
    const float* other      = (const float*)d_in[5];
    const float* char_table = (const float*)d_in[6];
    const float* filter_w   = (const float*)d_in[7];
    const float* filter_b   = (const float*)d_in[8];
    const float* gate_w     = (const float*)d_in[9];
    const float* gate_b     = (const float*)d_in[10];
    const float* mlp_w      = (const float*)d_in[11];
    const float* mlp_b      = (const float*)d_in[12];
    const float* kw_table   = (const float*)d_in[13];
    const float* aline_w    = (const float*)d_in[14];
    const float* aline_b    = (const float*)d_in[15];
    const float* t1_attn_w  = (const float*)d_in[16];
    const float* t1_attn_b  = (const float*)d_in[17];
    const float* t1_ffn_w1  = (const float*)d_in[18];
    const float* t1_ffn_b1  = (const float*)d_in[19];
    const float* t1_ffn_w2  = (const float*)d_in[20];
    const float* t1_ffn_b2  = (const float*)d_in[21];
    const float* t1_ln_g    = (const float*)d_in[22];
    const float* t1_ln_b    = (const float*)d_in[23];
    const float* t2_attn_w  = (const float*)d_in[24];
    const float* t2_attn_b  = (const float*)d_in[25];
    const float* t2_ffn_w1  = (const float*)d_in[26];
    const float* t2_ffn_b1  = (const float*)d_in[27];
    const float* t2_ffn_w2  = (const float*)d_in[28];
    const float* t2_ffn_b2  = (const float*)d_in[29];
    const float* t2_ln_g    = (const float*)d_in[30];
    const float* t2_ln_b    = (const float*)d_in[31];
    const float* reg_w1     = (const float*)d_in[32];
    const float* reg_b1     = (const float*)d_in[33];
    const float* reg_w2     = (const float*)d_in[34];
    const float* reg_b2     = (const float*)d_in[35];

    float* ws   = (float*)d_ws;
    float* tblS = ws;                    // 32768
    float* x1   = tblS + 32768;          // 768*256  = 196608
    float* qkv  = x1 + 196608;           // 768*768  = 589824
    float* obuf = qkv + 589824;          // 196608
    float* abuf = obuf + 196608;         // 196608
    float* hbuf = abuf + 196608;         // 768*2048 = 1572864
    float* x2   = hbuf + 1572864;        // 192*272  = 52224
    float* realb= x2 + 52224;            // 16*272   = 4352
    float* pbuf = qkv;                   // split-K partial region

    auto gemm = [&](const float* A, const float* W, const float* bias, float* Cc,
                    int R, int K, int N, int relu) {
        dim3 g((N + BN - 1) / BN, (R + BM - 1) / BM, 1);
        gemm64_k<<<g, 256, 0, stream>>>(A, W, bias, Cc, R, K, N, relu, K);
    };
    auto gemm_split = [&](const float* A, const float* W, const float* bias, float* Cc,
                          int R, int K, int N, int relu, int ns) {
        int ksl = ((K + ns - 1) / ns + BKT - 1) / BKT * BKT;
        dim3 g((N + BN - 1) / BN, (R + BM - 1) / BM, ns);
        gemm64_k<<<g, 256, 0, stream>>>(A, W, bias, pbuf, R, K, N, 0, ksl);
        int tot = R * N;
        reduce_bias_k<<<(tot + 255) / 256, 256, 0, stream>>>(pbuf, bias, Cc, R, N, ns, relu);
    };

    scale_table_k<<<128, 256, 0, stream>>>(char_table, tblS);
    attvec_k<<<NSTR_, 256, 0, stream>>>(chars, att_type, kw_idx, tblS,
                                        filter_w, filter_b, gate_w, gate_b,
                                        mlp_w, mlp_b, kw_table, aline_w, aline_b, x1);

    // ---- transformer 1: seq=12, batch=64, d=256 ----
    for (int i = 0; i < 2; ++i) {
        const float* aw = t1_attn_w + (size_t)i * 4 * C_ * C_;
        const float* ab = t1_attn_b + (size_t)i * 4 * C_;
        gemm(x1, aw, ab, qkv, 768, C_, 3 * C_, 0);
        attn_k<<<64, 256, 0, stream>>>(qkv, obuf, 12, 64, C_, 0.0625f);
        gemm(obuf, aw + 3 * C_ * C_, ab + 3 * C_, abuf, 768, C_, C_, 0);
        add_ln_k<<<768, 256, 0, stream>>>(x1, abuf, t1_ln_g + i * 2 * C_, t1_ln_b + i * 2 * C_, C_);
        gemm(x1, t1_ffn_w1 + (size_t)i * FF_ * C_, t1_ffn_b1 + i * FF_, hbuf, 768, C_, FF_, 1);
        gemm_split(hbuf, t1_ffn_w2 + (size_t)i * C_ * FF_, t1_ffn_b2 + i * C_, abuf, 768, FF_, C_, 0, 4);
        add_ln_k<<<768, 256, 0, stream>>>(x1, abuf, t1_ln_g + i * 2 * C_ + C_, t1_ln_b + i * 2 * C_ + C_, C_);
    }

    build_x2_k<<<192, 256, 0, stream>>>(x1, stat, x2);

    // ---- transformer 2: seq=8, batch=24, d=272 ----
    float sc2 = 1.0f / sqrtf(272.0f);
    for (int i = 0; i < 2; ++i) {
        const float* aw = t2_attn_w + (size_t)i * 4 * D2_ * D2_;
        const float* ab = t2_attn_b + (size_t)i * 4 * D2_;
        gemm(x2, aw, ab, qkv, 192, D2_, 3 * D2_, 0);
        attn_k<<<24, 256, 0, stream>>>(qkv, obuf, 8, 24, D2_, sc2);
        gemm(obuf, aw + 3 * D2_ * D2_, ab + 3 * D2_, abuf, 192, D2_, D2_, 0);
        add_ln_k<<<192, 256, 0, stream>>>(x2, abuf, t2_ln_g + i * 2 * D2_, t2_ln_b + i * 2 * D2_, D2_);
        gemm(x2, t2_ffn_w1 + (size_t)i * FF_ * D2_, t2_ffn_b1 + i * FF_, hbuf, 192, D2_, FF_, 1);
        gemm_split(hbuf, t2_ffn_w2 + (size_t)i * D2_ * FF_, t2_ffn_b2 + i * D2_, abuf, 192, FF_, D2_, 0, 8);
        add_ln_k<<<192, 256, 0, stream>>>(x2, abuf, t2_ln_g + i * 2 * D2_ + D2_, t2_ln_b + i * 2 * D2_ + D2_, D2_);
    }

    build_real_k<<<16, 256, 0, stream>>>(x2, realb);
    regressor_k<<<8, 256, 0, stream>>>(realb, input_idx, kw_table, other,
                                       reg_w1, reg_b1, reg_w2, reg_b2, (float*)d_out);
}